// Round 10
// baseline (294.039 us; speedup 1.0000x reference)
//
#include <hip/hip_runtime.h>

typedef __bf16 bf16;
typedef __bf16 bf16x4 __attribute__((ext_vector_type(4)));
typedef __bf16 bf16x8 __attribute__((ext_vector_type(8)));
typedef float  f32x4  __attribute__((ext_vector_type(4)));

// B=2, N=2048, QN=512, D=QD=1024, H=QH=16, HD=64. fp32 in/out, bf16 MFMA.

#define AS1(p) ((const __attribute__((address_space(1))) void*)(p))
#define AS3(p) ((__attribute__((address_space(3))) void*)(p))
__device__ __forceinline__ void gl16(const void* g, void* l) {
    __builtin_amdgcn_global_load_lds(AS1(g), AS3(l), 16, 0, 0);
}
// soft barriers: per-wave bounded vmcnt wait; prefetch loads stay in flight.
#define BAR_VM4() asm volatile("s_waitcnt vmcnt(4)\n\ts_barrier" ::: "memory")
#define BAR_VM2() asm volatile("s_waitcnt vmcnt(2)\n\ts_barrier" ::: "memory")
#define BAR_VM0() asm volatile("s_waitcnt vmcnt(0)\n\ts_barrier" ::: "memory")
#define BAR()     asm volatile("s_barrier" ::: "memory")

// ---------------------------------------------------------------------------
// prep: fused cast (blocks 0..2559) + weight-transpose (2560..5119) + lr_out
// (5120..5247). All independent input-only work -> one launch.
// ---------------------------------------------------------------------------
__global__ __launch_bounds__(256) void prep(
    const float* __restrict__ x, bf16* __restrict__ xb,
    const float* __restrict__ query, bf16* __restrict__ qryb,
    const float* __restrict__ W_qkv, const float* __restrict__ W_xkv,
    const float* __restrict__ W_qlin, const float* __restrict__ W_proj,
    const float* __restrict__ W_qproj,
    bf16* __restrict__ WtX, bf16* __restrict__ Wtqlin,
    bf16* __restrict__ Wtproj, bf16* __restrict__ Wtqproj,
    const float* __restrict__ lowres, const float* __restrict__ W_lr,
    const float* __restrict__ b_lr, float* __restrict__ lrout)
{
    __shared__ float T[64][65];
    const int bid = blockIdx.x, tid = threadIdx.x;

    if (bid < 2560) {
        // ---- fp32 -> bf16 cast for x and query ----
        int idx = (bid * 256 + tid) << 3;
        const float* s; bf16* d;
        if (idx < 4194304) { s = x + idx; d = xb + idx; }
        else { int k = idx - 4194304; s = query + k; d = qryb + k; }
        f32x4 a = *(const f32x4*)s, c = *(const f32x4*)(s + 4);
        bf16x8 v;
#pragma unroll
        for (int j = 0; j < 4; j++) { v[j] = (bf16)a[j]; v[4 + j] = (bf16)c[j]; }
        *(bf16x8*)d = v;
    } else if (bid < 5120) {
        // ---- weights [1024][N] fp32 -> bf16 transposed [N][1024] ----
        int w = bid - 2560;
        int gx = w % 160, k0 = (w / 160) << 6;
        const float* S; bf16* D; int N;
        if (gx < 48)       { S = W_qkv;   D = WtX;     N = 3072; }
        else if (gx < 80)  { S = W_xkv;   D = WtX + (size_t)3072 * 1024; N = 2048; gx -= 48; }
        else if (gx < 128) { S = W_qlin;  D = Wtqlin;  N = 3072; gx -= 80; }
        else if (gx < 144) { S = W_proj;  D = Wtproj;  N = 1024; gx -= 128; }
        else               { S = W_qproj; D = Wtqproj; N = 1024; gx -= 144; }
        int n0 = gx << 6;
#pragma unroll
        for (int rr = 0; rr < 4; rr++) {
            int row = (rr << 4) + (tid >> 4), col = (tid & 15) << 2;
            f32x4 v = *(const f32x4*)(S + (size_t)(k0 + row) * N + n0 + col);
#pragma unroll
            for (int j = 0; j < 4; j++) T[col + j][row] = v[j];
        }
        __syncthreads();
        {
            int n = tid >> 2, kc = (tid & 3) << 4;
            bf16x8 v0, v1;
#pragma unroll
            for (int j = 0; j < 8; j++) {
                v0[j] = (bf16)T[n][kc + j];
                v1[j] = (bf16)T[n][kc + 8 + j];
            }
            bf16* dp = D + (size_t)(n0 + n) * 1024 + k0 + kc;
            *(bf16x8*)dp = v0; *(bf16x8*)(dp + 8) = v1;
        }
    } else {
        // ---- lr_out[b,i,j] ----
        int idx = (bid - 5120) * 256 + tid;
        int j = idx & 63, i = (idx >> 6) & 255, b = idx >> 14;
        float acc = b_lr[j];
        const float* lr = lowres + ((size_t)b << 14);
        for (int k = 0; k < 64; k++) {
            int f = i * 64 + k;
            acc += lr[((f & 255) << 6) + (f >> 8)] * W_lr[(k << 6) + j];
        }
        lrout[idx] = acc;
    }
}

// ---------------------------------------------------------------------------
// GEMM core: C[M,N] = A[M,K] @ Bt[N,K]^T, 128x128 tile, BK=32, LDS
// double-buffered global_load_lds staging, soft barriers (vmcnt(4)).
// LDS swizzle: slot s of row r holds chunk s ^ ((r^(r>>2))&3)  (2-way, free).
// Epilogue staging uses stride-72 pad (36KB total). NOTE (round-9 lesson):
// occupancy here is VGPR-capped (88 -> 128-granule -> 4 blocks/CU), so
// shrinking LDS to 32KB buys nothing, while the stride-64 epilogue costs
// +2M bank-conflict cycles (+7us). Stride-72 is load-bearing.
// NSPLIT>0: epilogue scatters 64-col head-blocks into per-head buffers via
// LDS round-trip; vmask bit per split = write transposed [bh][hd][ntok].
// V outputs are written with per-32-token-tile group permutation pi^-1 so the
// flash kernel consumes P straight from the S-output register layout:
//   pi(8g+j) = 4g + (j&3) + 16*(j>>2).
// s0scale multiplies split 0 (pre-scales Q for attention).
// ---------------------------------------------------------------------------
template <int NSPLIT, typename OT>
__device__ __forceinline__ void gemm_core(
    bf16* gsm,
    const bf16* __restrict__ A, const bf16* __restrict__ Bt,
    OT* __restrict__ C0, OT* __restrict__ C1, OT* __restrict__ C2,
    OT* __restrict__ C3, OT* __restrict__ C4,
    const float* __restrict__ bias, int N, int K, int tshift,
    float s0scale, unsigned vmask, int bx, int by)
{
    const int tid  = threadIdx.x;
    const int wave = tid >> 6, lane = tid & 63;
    const int l15  = lane & 15, g = lane >> 4;
    const int wr   = wave & 1, wc = wave >> 1;
    const int m0   = by << 7, n0 = bx << 7;

    f32x4 acc[4][4] = {};

    auto stage = [&](int t, int bsel) {
        const bf16* Ab = A  + (size_t)m0 * K + (t << 5);
        const bf16* Bb = Bt + (size_t)n0 * K + (t << 5);
        char* Ad = (char*)gsm + (bsel << 14);
        char* Bd = Ad + 8192;
        const int wb = (tid & 192) << 4;
#pragma unroll
        for (int i = 0; i < 2; i++) {
            int L = (i << 8) + tid;
            int r = L >> 2, c = (L & 3) ^ ((r ^ (r >> 2)) & 3);
            gl16(Ab + (size_t)r * K + (c << 3), Ad + (i << 12) + wb);
            gl16(Bb + (size_t)r * K + (c << 3), Bd + (i << 12) + wb);
        }
    };
    auto compute = [&](int bsel) {
        const char* Ad = (const char*)gsm + (bsel << 14);
        const char* Bd = Ad + 8192;
        bf16x8 af[4], bq[4];
#pragma unroll
        for (int mb = 0; mb < 4; mb++) {
            int row = (wr << 6) + (mb << 4) + l15;
            af[mb] = *(const bf16x8*)(Ad + (row << 6)
                      + ((g ^ ((row ^ (row >> 2)) & 3)) << 4));
        }
#pragma unroll
        for (int nb = 0; nb < 4; nb++) {
            int row = (wc << 6) + (nb << 4) + l15;
            bq[nb] = *(const bf16x8*)(Bd + (row << 6)
                      + ((g ^ ((row ^ (row >> 2)) & 3)) << 4));
        }
#pragma unroll
        for (int mb = 0; mb < 4; mb++)
#pragma unroll
            for (int nb = 0; nb < 4; nb++)
                acc[mb][nb] = __builtin_amdgcn_mfma_f32_16x16x32_bf16(
                    af[mb], bq[nb], acc[mb][nb], 0, 0, 0);
    };

    const int T = K >> 5;
    stage(0, 0);
    for (int t = 0; t < T; t++) {
        int bsel = t & 1;
        if (t + 1 < T) { stage(t + 1, bsel ^ 1); BAR_VM4(); }
        else           { BAR_VM0(); }
        compute(bsel);
        BAR();
    }

    if constexpr (NSPLIT == 0) {
#pragma unroll
        for (int mb = 0; mb < 4; mb++)
#pragma unroll
            for (int nb = 0; nb < 4; nb++) {
                int n = n0 + (wc << 6) + (nb << 4) + l15;
                int mbase = m0 + (wr << 6) + (mb << 4) + (g << 2);
                float bi = bias[n];
#pragma unroll
                for (int r = 0; r < 4; r++)
                    C0[(size_t)(mbase + r) * N + n] = (OT)(acc[mb][nb][r] + bi);
            }
    } else {
        BAR();
        bf16* stg = gsm + wave * 4608;
        const int nh = (n0 >> 6) + wc;
        const int sl = nh >> 4, hq = nh & 15;
        const float scl = (sl == 0) ? s0scale : 1.0f;
        const bool isv = (vmask >> sl) & 1;
        if (isv) {   // stage transposed [hd][t], stride 72
#pragma unroll
            for (int mb = 0; mb < 4; mb++)
#pragma unroll
                for (int nb = 0; nb < 4; nb++)
#pragma unroll
                    for (int r = 0; r < 4; r++)
                        stg[((nb << 4) + l15) * 72 + (mb << 4) + (g << 2) + r]
                            = (bf16)(acc[mb][nb][r] * scl);
        } else {     // stage [t][hd], stride 64
#pragma unroll
            for (int mb = 0; mb < 4; mb++)
#pragma unroll
                for (int nb = 0; nb < 4; nb++)
#pragma unroll
                    for (int r = 0; r < 4; r++)
                        stg[((mb << 4) + (g << 2) + r) << 6 | ((nb << 4) + l15)]
                            = (bf16)(acc[mb][nb][r] * scl);
        }
        __syncthreads();
        const int ntok = 1 << tshift;
        const int tok0 = m0 + (wr << 6);
        const int b = tok0 >> tshift, t0 = tok0 & (ntok - 1);
        const int bh_ = (b << 4) + hq;
        OT* dst = (sl == 0) ? C0 : (sl == 1) ? C1 : (sl == 2) ? C2
                : (sl == 3) ? C3 : C4;
#pragma unroll
        for (int rr = 0; rr < 8; rr++) {
            int idx = (rr << 6) + lane;
            int rowi = idx >> 3, c = idx & 7;
            if (isv) {
                // pi-permuted store: tokens in 4-groups; group gamma goes to
                // position group piinv(gamma) = 2*(gamma&3) + (gamma>>2).
                bf16x8 vv = *(const bf16x8*)&stg[rowi * 72 + (c << 3)];
                bf16x4 lo, hi;
#pragma unroll
                for (int jj = 0; jj < 4; jj++) { lo[jj] = vv[jj]; hi[jj] = vv[4 + jj]; }
                int tb = t0 + ((c >> 2) << 5);          // 32-token tile base
                int gamma0 = (c << 1) & 7;              // even token-group
                int p_lo = (((gamma0 & 3) << 1) + (gamma0 >> 2)) << 2;
                size_t base = ((size_t)((bh_ << 6) + rowi)) * ntok + tb;
                *(bf16x4*)&dst[base + p_lo] = lo;
                *(bf16x4*)&dst[base + p_lo + 8] = hi;
            } else {
                bf16x8 vv = *(const bf16x8*)&stg[(rowi << 6) + (c << 3)];
                *(bf16x8*)&dst[(((size_t)bh_ * ntok + t0 + rowi) << 6) + (c << 3)] = vv;
            }
        }
    }
}

// ---------------------------------------------------------------------------
// Fused front GEMMs, 2D-supertile XCD swizzle. 1472 = 8 XCDs x 184 slots.
// GEMM1 (x @ [W_qkv|W_xkv], 40x32 tiles): slot s<160 -> XCD owns a 5-wide
// bx column band (B working set 1.3MB stays L2-resident); within it, 4x5
// supertiles sweep by. bx = 5*xcd + s%5, by = 4*(s/20) + (s%20)/5.
// GEMM2 (query @ W_qlin, 24x8 tiles): s>=160 -> by = xcd, bx = s-160.
// ---------------------------------------------------------------------------
__global__ __launch_bounds__(256) void gemm_qkv(
    const bf16* __restrict__ A0, const bf16* __restrict__ Bt0,
    bf16* __restrict__ qb, bf16* __restrict__ kb, bf16* __restrict__ vbt,
    bf16* __restrict__ k2, bf16* __restrict__ v2t,
    const bf16* __restrict__ A1, const bf16* __restrict__ Bt1,
    bf16* __restrict__ qq, bf16* __restrict__ qk, bf16* __restrict__ qvt,
    float sc2)
{
    __shared__ __align__(16) bf16 gsm[18432];
    const int xcd = blockIdx.x & 7, s = blockIdx.x >> 3;
    const bf16 *A, *Bt; bf16 *C0, *C1, *C2, *C3, *C4;
    int N, tshift, bx, by; unsigned vmask;
    if (s < 160) {
        int k = s / 20, w = s % 20;
        by = (k << 2) + w / 5; bx = xcd * 5 + w % 5;
        A = A0; Bt = Bt0; C0 = qb; C1 = kb; C2 = vbt; C3 = k2; C4 = v2t;
        N = 5120; tshift = 11; vmask = 0b10100u;
    } else {
        by = xcd; bx = s - 160;
        A = A1; Bt = Bt1; C0 = qq; C1 = qk; C2 = qvt; C3 = nullptr; C4 = nullptr;
        N = 3072; tshift = 9; vmask = 0b100u;
    }
    gemm_core<1, bf16>(gsm, A, Bt, C0, C1, C2, C3, C4, nullptr,
                       N, 1024, tshift, sc2, vmask, bx, by);
}

// ---------------------------------------------------------------------------
// Fused output projections: ax @ W_proj (256 blocks, grid 8x32) and
// aq @ W_qproj (64 blocks, grid 8x8), one launch.
// XCD-chunked swizzle (320 = 8*40): per-XCD chunk = 5 A-bands (1.3MB) +
// B (2MB) -> fully L2-resident.
// ---------------------------------------------------------------------------
__global__ __launch_bounds__(256) void gemm_proj(
    const bf16* __restrict__ ax, const bf16* __restrict__ Wtp,
    float* __restrict__ o0, const float* __restrict__ bp,
    const bf16* __restrict__ aq, const bf16* __restrict__ Wtq,
    float* __restrict__ o1, const float* __restrict__ bq)
{
    __shared__ __align__(16) bf16 gsm[18432];
    int idx = (blockIdx.x & 7) * 40 + (blockIdx.x >> 3);
    const bf16 *A, *Bt; float* C; const float* bias; int bx, by;
    if (idx < 256) { A = ax; Bt = Wtp; C = o0; bias = bp; bx = idx & 7; by = idx >> 3; }
    else { idx -= 256; A = aq; Bt = Wtq; C = o1; bias = bq; bx = idx & 7; by = idx >> 3; }
    gemm_core<0, float>(gsm, A, Bt, C, nullptr, nullptr, nullptr, nullptr, bias,
                        1024, 1024, 0, 1.0f, 0u, bx, by);
}

// ---------------------------------------------------------------------------
// Merged flash attention, S^T form, q-tile 128 over 4 waves (32 q/wave),
// k-tile 32, fixed-max softmax (Q pre-scaled to log2 domain), double-buffered
// global_load_lds K/V staging, soft barriers (vmcnt(2), never drained).
// P stays fully in registers: Vt is stored pi-permuted (see gemm_core), so the
// S-output register layout IS the PV B-operand layout (zero P data movement).
// Rowsums via ones-MFMA: Lones[qb] = mfma(ones, pf[qb], Lones[qb]) makes every
// lane's accumulator hold sum_k P[k][q=l15] (accumulated across steps, no VALU
// adds, no shuffles).  Staging uses per-thread incremental global pointers.
// s_setprio(1) wraps the MFMA clusters (T5): ~2.5 independent blocks/CU at
// unsynchronized phases -> scheduler favors MFMA-entering waves.
// Grid 640 = 8 XCDs x 80. Decode: xcd j = blockIdx&7, slot i = blockIdx>>3.
//   i < 16 : cross-attn (longest first), bh = 4j + (i>>2), qtile = i&3;
//            seg0 = x-KV nk=2048 * tanh(gate), seg1 = q-KV nk=512 weight 1.
//   i >= 16: self-attn, bh = 4j + ((i-16)>>4), qtile = (i-16)&15, nk=2048.
// Q [bh][nq][64], K [bh][nk][64], Vt' [bh][64][nk] (pi-permuted),
// O [b][nq][16*64].  LDS 17.4KB: K 2x4KB | V 2x4KB (epilogue reuses as OB).
// ---------------------------------------------------------------------------
__global__ __launch_bounds__(256) void flash3m(
    const bf16* __restrict__ Q1, const bf16* __restrict__ K1,
    const bf16* __restrict__ V1t, bf16* __restrict__ O1,
    const bf16* __restrict__ Q2, const bf16* __restrict__ K2a,
    const bf16* __restrict__ V2at, const bf16* __restrict__ K2b,
    const bf16* __restrict__ V2bt, bf16* __restrict__ O2,
    const float* __restrict__ gate)
{
    // bytes: K bufs [0,8192), V bufs [8192,16384); epilogue OB [0,17408)
    __shared__ __align__(16) bf16 fsm[8704];

    const int tid = threadIdx.x;
    const int wave = tid >> 6, lane = tid & 63;
    const int l15 = lane & 15, g = lane >> 4;

    const int j = blockIdx.x & 7, i = blockIdx.x >> 3;
    const bf16 *Qp, *Ka, *Vat, *Kb2, *Vbt2; bf16* Op;
    int nq, nk1, nk2, q0, bh;
    bool cross;
    if (i < 16) {
        cross = true;
        bh = (j << 2) + (i >> 2); q0 = (i & 3) << 7;
        Qp = Q2; Ka = K2a; Vat = V2at; Kb2 = K2b; Vbt2 = V2bt; Op = O2;
        nq = 512; nk1 = 2048; nk2 = 512;
    } else {
        cross = false;
        int is = i - 16;
        bh = (j << 2) + (is >> 4); q0 = (is & 15) << 7;
        Qp = Q1; Ka = K1; Vat = V1t; Kb2 = nullptr; Vbt2 = nullptr; Op = O1;
        nq = 2048; nk1 = 2048; nk2 = 0;
    }
    const int h = bh & 15, b = bh >> 4;
    const int T1 = nk1 >> 5, T = T1 + (cross ? (nk2 >> 5) : 0);

    // Q frags straight from global: B-operand, n=l15 (q), k=ks*32+g*8+j
    bf16x8 qf[2][2];
#pragma unroll
    for (int qb = 0; qb < 2; qb++) {
        const bf16* qrow = Qp + ((size_t)bh * nq + q0 + (wave << 5) + (qb << 4) + l15) * 64;
        qf[qb][0] = *(const bf16x8*)(qrow + (g << 3));
        qf[qb][1] = *(const bf16x8*)(qrow + 32 + (g << 3));
    }

    // all-ones A-fragment for the rowsum MFMA
    bf16x8 ones;
#pragma unroll
    for (int z = 0; z < 8; z++) ones[z] = (bf16)1.0f;

    f32x4 Oacc[4][2] = {}, Ofin[4][2] = {};
    f32x4 Lones[2] = {};            // rowsum accumulators (all lanes replicated)
    const float gmul = cross ? tanhf(gate[h]) : 1.0f;

    // per-thread incremental staging pointers
    const int kr = tid >> 3, kc = (tid & 7) ^ (kr & 7);
    const int vr = tid >> 2, vc = (tid & 3) ^ (vr & 3);
    const bf16* kaddr = Ka + ((size_t)bh * nk1) * 64 + (kr << 6) + (kc << 3);
    const bf16* vaddr = Vat + ((size_t)bh << 6) * nk1 + (size_t)vr * nk1 + (vc << 3);
    int staged = 0;

    auto stage = [&](int bsel) {
        if (cross && staged == T1) {   // switch to q-KV segment
            kaddr = Kb2 + ((size_t)bh * nk2) * 64 + (kr << 6) + (kc << 3);
            vaddr = Vbt2 + ((size_t)bh << 6) * nk2 + (size_t)vr * nk2 + (vc << 3);
        }
        char* Kd = (char*)fsm + (bsel << 12);
        char* Vd = (char*)fsm + 8192 + (bsel << 12);
        const int wb = (tid & 192) << 4;
        gl16(kaddr, Kd + wb);
        gl16(vaddr, Vd + wb);
        kaddr += 2048;    // 32 rows x 64
        vaddr += 32;      // 32 tokens
        staged++;
    };

    auto compute = [&](int t, int bsel) {
        const char* Kb = (const char*)fsm + (bsel << 12);
        const char* Vb = (const char*)fsm + 8192 + (bsel << 12);
        // S^T = K Q^T : 8 MFMAs. Lane (l15,g) gets tokens 4g+r (nb=0),
        // 16+4g+r (nb=1) for q=l15.
        f32x4 S[2][2];
        __builtin_amdgcn_s_setprio(1);
#pragma unroll
        for (int nb = 0; nb < 2; nb++) {
            int row = (nb << 4) + l15;
            bf16x8 kf0 = *(const bf16x8*)(Kb + (row << 7) + ((g ^ (row & 7)) << 4));
            bf16x8 kf1 = *(const bf16x8*)(Kb + (row << 7) + (((4 + g) ^ (row & 7)) << 4));
#pragma unroll
            for (int qb = 0; qb < 2; qb++) {
                f32x4 s = {};
                s = __builtin_amdgcn_mfma_f32_16x16x32_bf16(kf0, qf[qb][0], s, 0, 0, 0);
                s = __builtin_amdgcn_mfma_f32_16x16x32_bf16(kf1, qf[qb][1], s, 0, 0, 0);
                S[nb][qb] = s;
            }
        }
        __builtin_amdgcn_s_setprio(0);
        // exp2 -> P straight into B-frag registers (pi-matched V layout)
        bf16x8 pf[2];
#pragma unroll
        for (int qb = 0; qb < 2; qb++)
#pragma unroll
            for (int r = 0; r < 4; r++) {
                pf[qb][r]     = (bf16)__builtin_amdgcn_exp2f(S[0][qb][r]);
                pf[qb][4 + r] = (bf16)__builtin_amdgcn_exp2f(S[1][qb][r]);
            }
        __builtin_amdgcn_s_setprio(1);
        // rowsums via ones-MFMA (accumulates across steps; every lane holds
        // sum_k P[k][q=l15] in all 4 accumulator slots)
#pragma unroll
        for (int qb = 0; qb < 2; qb++)
            Lones[qb] = __builtin_amdgcn_mfma_f32_16x16x32_bf16(
                ones, pf[qb], Lones[qb], 0, 0, 0);
        // O^T += Vt' @ P^T : 8 MFMAs
#pragma unroll
        for (int hb = 0; hb < 4; hb++) {
            int row = (hb << 4) + l15;
            bf16x8 vf = *(const bf16x8*)(Vb + (row << 6) + ((g ^ (row & 3)) << 4));
#pragma unroll
            for (int qb = 0; qb < 2; qb++)
                Oacc[hb][qb] = __builtin_amdgcn_mfma_f32_16x16x32_bf16(
                    vf, pf[qb], Oacc[hb][qb], 0, 0, 0);
        }
        __builtin_amdgcn_s_setprio(0);
        if (cross && t == T1 - 1) {   // gated-segment flush
#pragma unroll
            for (int qb = 0; qb < 2; qb++) {
                float w = gmul / Lones[qb][0];
#pragma unroll
                for (int hb = 0; hb < 4; hb++)
#pragma unroll
                    for (int r = 0; r < 4; r++) {
                        Ofin[hb][qb][r] += Oacc[hb][qb][r] * w;
                        Oacc[hb][qb][r] = 0.0f;
                    }
                Lones[qb] = f32x4{};
            }
        }
    };

    stage(0);
    for (int t = 0; t < T; t++) {
        int bsel = t & 1;
        if (t + 1 < T) { stage(bsel ^ 1); BAR_VM2(); }
        else           { BAR_VM0(); }
        compute(t, bsel);
        BAR();
    }

    // final weights (rowsums already reduced by the ones-MFMA)
    float wfin[2];
#pragma unroll
    for (int qb = 0; qb < 2; qb++)
        wfin[qb] = (cross ? 1.0f : gmul) / Lones[qb][0];

    // epilogue: O^T regs -> LDS [hd=64][q=128] stride 136 -> coalesced stores
    bf16* OB = fsm;
#pragma unroll
    for (int hb = 0; hb < 4; hb++)
#pragma unroll
        for (int qb = 0; qb < 2; qb++)
#pragma unroll
            for (int r = 0; r < 4; r++) {
                float v = Oacc[hb][qb][r] * wfin[qb];
                if (cross) v += Ofin[hb][qb][r];
                OB[((hb << 4) + (g << 2) + r) * 136 + (wave << 5) + (qb << 4) + l15] = (bf16)v;
            }
    __syncthreads();
    {
        int q = tid >> 1, half = (tid & 1) << 5;
        bf16x8 o[4];
#pragma unroll
        for (int j2 = 0; j2 < 4; j2++)
#pragma unroll
            for (int jj = 0; jj < 8; jj++)
                o[j2][jj] = OB[(half + (j2 << 3) + jj) * 136 + q];
        bf16* op = Op + (((size_t)b * nq + q0 + q) << 10) + (h << 6) + half;
#pragma unroll
        for (int j2 = 0; j2 < 4; j2++)
            *(bf16x8*)(op + (j2 << 3)) = o[j2];
    }
}

// ---------------------------------------------------------------------------
extern "C" void kernel_launch(void* const* d_in, const int* in_sizes, int n_in,
                              void* d_out, int out_size, void* d_ws, size_t ws_size,
                              hipStream_t stream)
{
    const float* x       = (const float*)d_in[0];
    const float* query   = (const float*)d_in[1];
    const float* lowres  = (const float*)d_in[2];
    const float* W_qkv   = (const float*)d_in[3];
    const float* W_xkv   = (const float*)d_in[4];
    const float* W_qlin  = (const float*)d_in[5];
    const float* gate    = (const float*)d_in[6];
    const float* W_proj  = (const float*)d_in[7];
    const float* b_proj  = (const float*)d_in[8];
    const float* W_qproj = (const float*)d_in[9];
    const float* b_qproj = (const float*)d_in[10];
    const float* W_lr    = (const float*)d_in[11];
    const float* b_lr    = (const float*)d_in[12];
    float* out = (float*)d_out;

    const float sc2 = 0.125f * 1.44269504088896f;   // scale*log2e, folded into Q

    char* ws = (char*)d_ws;
    bf16* WtX     = (bf16*)ws; ws += 10485760;  // [5120][1024] = qkv|xkv transposed
    bf16* Wtqlin  = (bf16*)ws; ws += 6291456;
    bf16* Wtproj  = (bf16*)ws; ws += 2097152;
    bf16* Wtqproj = (bf16*)ws; ws += 2097152;
    bf16* xb      = (bf16*)ws; ws += 8388608;   // ax aliases (xb dead by then)
    bf16* qryb    = (bf16*)ws; ws += 2097152;   // aq aliases
    bf16* qb      = (bf16*)ws; ws += 8388608;
    bf16* kb      = (bf16*)ws; ws += 8388608;
    bf16* vbt     = (bf16*)ws; ws += 8388608;   // [bh][64][2048] pi-permuted
    bf16* k2      = (bf16*)ws; ws += 8388608;
    bf16* v2t     = (bf16*)ws; ws += 8388608;   // [bh][64][2048] pi-permuted
    bf16* qq      = (bf16*)ws; ws += 2097152;
    bf16* qk      = (bf16*)ws; ws += 2097152;
    bf16* qvt     = (bf16*)ws; ws += 2097152;   // [bh][64][512] pi-permuted
    bf16* ax = xb;
    bf16* aq = qryb;

    // 1: casts + weight transposes + lr_out (all input-only)
    prep<<<5248, 256, 0, stream>>>(
        x, xb, query, qryb, W_qkv, W_xkv, W_qlin, W_proj, W_qproj,
        WtX, Wtqlin, Wtproj, Wtqproj, lowres, W_lr, b_lr, out + 5242880);

    // 2: x @ [W_qkv|W_xkv] -> q,k,v,k2,v2  +  query @ W_qlin -> qq,qk,qv
    gemm_qkv<<<1472, 256, 0, stream>>>(
        xb, WtX, qb, kb, vbt, k2, v2t, qryb, Wtqlin, qq, qk, qvt, sc2);

    // 3: merged attention: 512 self-attn + 128 cross-attn blocks, XCD-balanced
    flash3m<<<640, 256, 0, stream>>>(
        qb, kb, vbt, ax, qq, k2, v2t, qk, qvt, aq, gate);

    // 4: output projections
    gemm_proj<<<320, 256, 0, stream>>>(
        ax, Wtproj, out, b_proj, aq, Wtqproj, out + 4194304, b_qproj);

    (void)in_sizes; (void)n_in; (void)out_size; (void)ws_size;
}

// Round 11
// 284.841 us; speedup vs baseline: 1.0323x; 1.0323x over previous
//
#include <hip/hip_runtime.h>

typedef __bf16 bf16;
typedef __bf16 bf16x4 __attribute__((ext_vector_type(4)));
typedef __bf16 bf16x8 __attribute__((ext_vector_type(8)));
typedef float  f32x4  __attribute__((ext_vector_type(4)));

// B=2, N=2048, QN=512, D=QD=1024, H=QH=16, HD=64. fp32 in/out, bf16 MFMA.

#define AS1(p) ((const __attribute__((address_space(1))) void*)(p))
#define AS3(p) ((__attribute__((address_space(3))) void*)(p))
__device__ __forceinline__ void gl16(const void* g, void* l) {
    __builtin_amdgcn_global_load_lds(AS1(g), AS3(l), 16, 0, 0);
}
// soft barriers: per-wave bounded vmcnt wait; prefetch loads stay in flight.
#define BAR_VM4() asm volatile("s_waitcnt vmcnt(4)\n\ts_barrier" ::: "memory")
#define BAR_VM2() asm volatile("s_waitcnt vmcnt(2)\n\ts_barrier" ::: "memory")
#define BAR_VM0() asm volatile("s_waitcnt vmcnt(0)\n\ts_barrier" ::: "memory")
#define BAR()     asm volatile("s_barrier" ::: "memory")

// ---------------------------------------------------------------------------
// prep: fused cast (blocks 0..2559) + weight-transpose (2560..5119) + lr_out
// (5120..5247). All independent input-only work -> one launch.
// ---------------------------------------------------------------------------
__global__ __launch_bounds__(256) void prep(
    const float* __restrict__ x, bf16* __restrict__ xb,
    const float* __restrict__ query, bf16* __restrict__ qryb,
    const float* __restrict__ W_qkv, const float* __restrict__ W_xkv,
    const float* __restrict__ W_qlin, const float* __restrict__ W_proj,
    const float* __restrict__ W_qproj,
    bf16* __restrict__ WtX, bf16* __restrict__ Wtqlin,
    bf16* __restrict__ Wtproj, bf16* __restrict__ Wtqproj,
    const float* __restrict__ lowres, const float* __restrict__ W_lr,
    const float* __restrict__ b_lr, float* __restrict__ lrout)
{
    __shared__ float T[64][65];
    const int bid = blockIdx.x, tid = threadIdx.x;

    if (bid < 2560) {
        // ---- fp32 -> bf16 cast for x and query ----
        int idx = (bid * 256 + tid) << 3;
        const float* s; bf16* d;
        if (idx < 4194304) { s = x + idx; d = xb + idx; }
        else { int k = idx - 4194304; s = query + k; d = qryb + k; }
        f32x4 a = *(const f32x4*)s, c = *(const f32x4*)(s + 4);
        bf16x8 v;
#pragma unroll
        for (int j = 0; j < 4; j++) { v[j] = (bf16)a[j]; v[4 + j] = (bf16)c[j]; }
        *(bf16x8*)d = v;
    } else if (bid < 5120) {
        // ---- weights [1024][N] fp32 -> bf16 transposed [N][1024] ----
        int w = bid - 2560;
        int gx = w % 160, k0 = (w / 160) << 6;
        const float* S; bf16* D; int N;
        if (gx < 48)       { S = W_qkv;   D = WtX;     N = 3072; }
        else if (gx < 80)  { S = W_xkv;   D = WtX + (size_t)3072 * 1024; N = 2048; gx -= 48; }
        else if (gx < 128) { S = W_qlin;  D = Wtqlin;  N = 3072; gx -= 80; }
        else if (gx < 144) { S = W_proj;  D = Wtproj;  N = 1024; gx -= 128; }
        else               { S = W_qproj; D = Wtqproj; N = 1024; gx -= 144; }
        int n0 = gx << 6;
#pragma unroll
        for (int rr = 0; rr < 4; rr++) {
            int row = (rr << 4) + (tid >> 4), col = (tid & 15) << 2;
            f32x4 v = *(const f32x4*)(S + (size_t)(k0 + row) * N + n0 + col);
#pragma unroll
            for (int j = 0; j < 4; j++) T[col + j][row] = v[j];
        }
        __syncthreads();
        {
            int n = tid >> 2, kc = (tid & 3) << 4;
            bf16x8 v0, v1;
#pragma unroll
            for (int j = 0; j < 8; j++) {
                v0[j] = (bf16)T[n][kc + j];
                v1[j] = (bf16)T[n][kc + 8 + j];
            }
            bf16* dp = D + (size_t)(n0 + n) * 1024 + k0 + kc;
            *(bf16x8*)dp = v0; *(bf16x8*)(dp + 8) = v1;
        }
    } else {
        // ---- lr_out[b,i,j] ----
        int idx = (bid - 5120) * 256 + tid;
        int j = idx & 63, i = (idx >> 6) & 255, b = idx >> 14;
        float acc = b_lr[j];
        const float* lr = lowres + ((size_t)b << 14);
        for (int k = 0; k < 64; k++) {
            int f = i * 64 + k;
            acc += lr[((f & 255) << 6) + (f >> 8)] * W_lr[(k << 6) + j];
        }
        lrout[idx] = acc;
    }
}

// ---------------------------------------------------------------------------
// GEMM core: C[M,N] = A[M,K] @ Bt[N,K]^T, 128x128 tile, BK=32, LDS
// double-buffered global_load_lds staging, soft barriers (vmcnt(4)).
// LDS swizzle: slot s of row r holds chunk s ^ ((r^(r>>2))&3)  (2-way, free).
// Epilogue staging uses stride-72 pad (36KB total). NOTE (round-9 lesson):
// occupancy here is VGPR-capped (88 -> 128-granule -> 4 blocks/CU), so
// shrinking LDS to 32KB buys nothing, while the stride-64 epilogue costs
// +2M bank-conflict cycles (+7us). Stride-72 is load-bearing.
// NSPLIT>0: epilogue scatters 64-col head-blocks into per-head buffers via
// LDS round-trip; vmask bit per split = write transposed [bh][hd][ntok].
// V outputs are written with per-32-token-tile group permutation pi^-1 so the
// flash kernel consumes P straight from the S-output register layout:
//   pi(8g+j) = 4g + (j&3) + 16*(j>>2).
// s0scale multiplies split 0 (pre-scales Q for attention).
// ---------------------------------------------------------------------------
template <int NSPLIT, typename OT>
__device__ __forceinline__ void gemm_core(
    bf16* gsm,
    const bf16* __restrict__ A, const bf16* __restrict__ Bt,
    OT* __restrict__ C0, OT* __restrict__ C1, OT* __restrict__ C2,
    OT* __restrict__ C3, OT* __restrict__ C4,
    const float* __restrict__ bias, int N, int K, int tshift,
    float s0scale, unsigned vmask, int bx, int by)
{
    const int tid  = threadIdx.x;
    const int wave = tid >> 6, lane = tid & 63;
    const int l15  = lane & 15, g = lane >> 4;
    const int wr   = wave & 1, wc = wave >> 1;
    const int m0   = by << 7, n0 = bx << 7;

    f32x4 acc[4][4] = {};

    auto stage = [&](int t, int bsel) {
        const bf16* Ab = A  + (size_t)m0 * K + (t << 5);
        const bf16* Bb = Bt + (size_t)n0 * K + (t << 5);
        char* Ad = (char*)gsm + (bsel << 14);
        char* Bd = Ad + 8192;
        const int wb = (tid & 192) << 4;
#pragma unroll
        for (int i = 0; i < 2; i++) {
            int L = (i << 8) + tid;
            int r = L >> 2, c = (L & 3) ^ ((r ^ (r >> 2)) & 3);
            gl16(Ab + (size_t)r * K + (c << 3), Ad + (i << 12) + wb);
            gl16(Bb + (size_t)r * K + (c << 3), Bd + (i << 12) + wb);
        }
    };
    auto compute = [&](int bsel) {
        const char* Ad = (const char*)gsm + (bsel << 14);
        const char* Bd = Ad + 8192;
        bf16x8 af[4], bq[4];
#pragma unroll
        for (int mb = 0; mb < 4; mb++) {
            int row = (wr << 6) + (mb << 4) + l15;
            af[mb] = *(const bf16x8*)(Ad + (row << 6)
                      + ((g ^ ((row ^ (row >> 2)) & 3)) << 4));
        }
#pragma unroll
        for (int nb = 0; nb < 4; nb++) {
            int row = (wc << 6) + (nb << 4) + l15;
            bq[nb] = *(const bf16x8*)(Bd + (row << 6)
                      + ((g ^ ((row ^ (row >> 2)) & 3)) << 4));
        }
#pragma unroll
        for (int mb = 0; mb < 4; mb++)
#pragma unroll
            for (int nb = 0; nb < 4; nb++)
                acc[mb][nb] = __builtin_amdgcn_mfma_f32_16x16x32_bf16(
                    af[mb], bq[nb], acc[mb][nb], 0, 0, 0);
    };

    const int T = K >> 5;
    stage(0, 0);
    for (int t = 0; t < T; t++) {
        int bsel = t & 1;
        if (t + 1 < T) { stage(t + 1, bsel ^ 1); BAR_VM4(); }
        else           { BAR_VM0(); }
        compute(bsel);
        BAR();
    }

    if constexpr (NSPLIT == 0) {
#pragma unroll
        for (int mb = 0; mb < 4; mb++)
#pragma unroll
            for (int nb = 0; nb < 4; nb++) {
                int n = n0 + (wc << 6) + (nb << 4) + l15;
                int mbase = m0 + (wr << 6) + (mb << 4) + (g << 2);
                float bi = bias[n];
#pragma unroll
                for (int r = 0; r < 4; r++)
                    C0[(size_t)(mbase + r) * N + n] = (OT)(acc[mb][nb][r] + bi);
            }
    } else {
        BAR();
        bf16* stg = gsm + wave * 4608;
        const int nh = (n0 >> 6) + wc;
        const int sl = nh >> 4, hq = nh & 15;
        const float scl = (sl == 0) ? s0scale : 1.0f;
        const bool isv = (vmask >> sl) & 1;
        if (isv) {   // stage transposed [hd][t], stride 72
#pragma unroll
            for (int mb = 0; mb < 4; mb++)
#pragma unroll
                for (int nb = 0; nb < 4; nb++)
#pragma unroll
                    for (int r = 0; r < 4; r++)
                        stg[((nb << 4) + l15) * 72 + (mb << 4) + (g << 2) + r]
                            = (bf16)(acc[mb][nb][r] * scl);
        } else {     // stage [t][hd], stride 64
#pragma unroll
            for (int mb = 0; mb < 4; mb++)
#pragma unroll
                for (int nb = 0; nb < 4; nb++)
#pragma unroll
                    for (int r = 0; r < 4; r++)
                        stg[((mb << 4) + (g << 2) + r) << 6 | ((nb << 4) + l15)]
                            = (bf16)(acc[mb][nb][r] * scl);
        }
        __syncthreads();
        const int ntok = 1 << tshift;
        const int tok0 = m0 + (wr << 6);
        const int b = tok0 >> tshift, t0 = tok0 & (ntok - 1);
        const int bh_ = (b << 4) + hq;
        OT* dst = (sl == 0) ? C0 : (sl == 1) ? C1 : (sl == 2) ? C2
                : (sl == 3) ? C3 : C4;
#pragma unroll
        for (int rr = 0; rr < 8; rr++) {
            int idx = (rr << 6) + lane;
            int rowi = idx >> 3, c = idx & 7;
            if (isv) {
                // pi-permuted store: tokens in 4-groups; group gamma goes to
                // position group piinv(gamma) = 2*(gamma&3) + (gamma>>2).
                bf16x8 vv = *(const bf16x8*)&stg[rowi * 72 + (c << 3)];
                bf16x4 lo, hi;
#pragma unroll
                for (int jj = 0; jj < 4; jj++) { lo[jj] = vv[jj]; hi[jj] = vv[4 + jj]; }
                int tb = t0 + ((c >> 2) << 5);          // 32-token tile base
                int gamma0 = (c << 1) & 7;              // even token-group
                int p_lo = (((gamma0 & 3) << 1) + (gamma0 >> 2)) << 2;
                size_t base = ((size_t)((bh_ << 6) + rowi)) * ntok + tb;
                *(bf16x4*)&dst[base + p_lo] = lo;
                *(bf16x4*)&dst[base + p_lo + 8] = hi;
            } else {
                bf16x8 vv = *(const bf16x8*)&stg[(rowi << 6) + (c << 3)];
                *(bf16x8*)&dst[(((size_t)bh_ * ntok + t0 + rowi) << 6) + (c << 3)] = vv;
            }
        }
    }
}

// ---------------------------------------------------------------------------
// Fused front GEMMs, 2D-supertile XCD swizzle. 1472 = 8 XCDs x 184 slots.
// GEMM1 (x @ [W_qkv|W_xkv], 40x32 tiles): slot s<160 -> XCD owns a 5-wide
// bx column band (B working set 1.3MB stays L2-resident); within it, 4x5
// supertiles sweep by. bx = 5*xcd + s%5, by = 4*(s/20) + (s%20)/5.
// GEMM2 (query @ W_qlin, 24x8 tiles): s>=160 -> by = xcd, bx = s-160.
// ---------------------------------------------------------------------------
__global__ __launch_bounds__(256) void gemm_qkv(
    const bf16* __restrict__ A0, const bf16* __restrict__ Bt0,
    bf16* __restrict__ qb, bf16* __restrict__ kb, bf16* __restrict__ vbt,
    bf16* __restrict__ k2, bf16* __restrict__ v2t,
    const bf16* __restrict__ A1, const bf16* __restrict__ Bt1,
    bf16* __restrict__ qq, bf16* __restrict__ qk, bf16* __restrict__ qvt,
    float sc2)
{
    __shared__ __align__(16) bf16 gsm[18432];
    const int xcd = blockIdx.x & 7, s = blockIdx.x >> 3;
    const bf16 *A, *Bt; bf16 *C0, *C1, *C2, *C3, *C4;
    int N, tshift, bx, by; unsigned vmask;
    if (s < 160) {
        int k = s / 20, w = s % 20;
        by = (k << 2) + w / 5; bx = xcd * 5 + w % 5;
        A = A0; Bt = Bt0; C0 = qb; C1 = kb; C2 = vbt; C3 = k2; C4 = v2t;
        N = 5120; tshift = 11; vmask = 0b10100u;
    } else {
        by = xcd; bx = s - 160;
        A = A1; Bt = Bt1; C0 = qq; C1 = qk; C2 = qvt; C3 = nullptr; C4 = nullptr;
        N = 3072; tshift = 9; vmask = 0b100u;
    }
    gemm_core<1, bf16>(gsm, A, Bt, C0, C1, C2, C3, C4, nullptr,
                       N, 1024, tshift, sc2, vmask, bx, by);
}

// ---------------------------------------------------------------------------
// Fused output projections: ax @ W_proj (256 blocks, grid 8x32) and
// aq @ W_qproj (64 blocks, grid 8x8), one launch.
// XCD-chunked swizzle (320 = 8*40): per-XCD chunk = 5 A-bands (1.3MB) +
// B (2MB) -> fully L2-resident.
// ---------------------------------------------------------------------------
__global__ __launch_bounds__(256) void gemm_proj(
    const bf16* __restrict__ ax, const bf16* __restrict__ Wtp,
    float* __restrict__ o0, const float* __restrict__ bp,
    const bf16* __restrict__ aq, const bf16* __restrict__ Wtq,
    float* __restrict__ o1, const float* __restrict__ bq)
{
    __shared__ __align__(16) bf16 gsm[18432];
    int idx = (blockIdx.x & 7) * 40 + (blockIdx.x >> 3);
    const bf16 *A, *Bt; float* C; const float* bias; int bx, by;
    if (idx < 256) { A = ax; Bt = Wtp; C = o0; bias = bp; bx = idx & 7; by = idx >> 3; }
    else { idx -= 256; A = aq; Bt = Wtq; C = o1; bias = bq; bx = idx & 7; by = idx >> 3; }
    gemm_core<0, float>(gsm, A, Bt, C, nullptr, nullptr, nullptr, nullptr, bias,
                        1024, 1024, 0, 1.0f, 0u, bx, by);
}

// ---------------------------------------------------------------------------
// Merged flash attention, S^T form, q-tile 128 over 4 waves (32 q/wave),
// k-tile 32, fixed-max softmax (Q pre-scaled to log2 domain), double-buffered
// global_load_lds K/V staging, soft barriers (vmcnt(2), never drained).
// P stays fully in registers: Vt is stored pi-permuted (see gemm_core), so the
// S-output register layout IS the PV B-operand layout (zero P data movement).
// Rowsums via ones-MFMA: Lones[qb] = mfma(ones, pf[qb], Lones[qb]) makes every
// lane's accumulator hold sum_k P[k][q=l15] (accumulated across steps, no VALU
// adds, no shuffles).  Staging uses per-thread incremental global pointers.
// NOTE (round-10 lesson): s_setprio around the MFMA clusters REGRESSED this
// kernel (80 -> 87.7us): the 4 waves are barrier-locked (no role diversity,
// T5 null regime) and the insertion perturbed regalloc (VGPR 80 -> 88,
// occupancy 19.4 -> 14.4). Do not re-add.
// Grid 640 = 8 XCDs x 80. Decode: xcd j = blockIdx&7, slot i = blockIdx>>3.
//   i < 16 : cross-attn (longest first), bh = 4j + (i>>2), qtile = i&3;
//            seg0 = x-KV nk=2048 * tanh(gate), seg1 = q-KV nk=512 weight 1.
//   i >= 16: self-attn, bh = 4j + ((i-16)>>4), qtile = (i-16)&15, nk=2048.
// Q [bh][nq][64], K [bh][nk][64], Vt' [bh][64][nk] (pi-permuted),
// O [b][nq][16*64].  LDS 17.4KB: K 2x4KB | V 2x4KB (epilogue reuses as OB).
// ---------------------------------------------------------------------------
__global__ __launch_bounds__(256) void flash3m(
    const bf16* __restrict__ Q1, const bf16* __restrict__ K1,
    const bf16* __restrict__ V1t, bf16* __restrict__ O1,
    const bf16* __restrict__ Q2, const bf16* __restrict__ K2a,
    const bf16* __restrict__ V2at, const bf16* __restrict__ K2b,
    const bf16* __restrict__ V2bt, bf16* __restrict__ O2,
    const float* __restrict__ gate)
{
    // bytes: K bufs [0,8192), V bufs [8192,16384); epilogue OB [0,17408)
    __shared__ __align__(16) bf16 fsm[8704];

    const int tid = threadIdx.x;
    const int wave = tid >> 6, lane = tid & 63;
    const int l15 = lane & 15, g = lane >> 4;

    const int j = blockIdx.x & 7, i = blockIdx.x >> 3;
    const bf16 *Qp, *Ka, *Vat, *Kb2, *Vbt2; bf16* Op;
    int nq, nk1, nk2, q0, bh;
    bool cross;
    if (i < 16) {
        cross = true;
        bh = (j << 2) + (i >> 2); q0 = (i & 3) << 7;
        Qp = Q2; Ka = K2a; Vat = V2at; Kb2 = K2b; Vbt2 = V2bt; Op = O2;
        nq = 512; nk1 = 2048; nk2 = 512;
    } else {
        cross = false;
        int is = i - 16;
        bh = (j << 2) + (is >> 4); q0 = (is & 15) << 7;
        Qp = Q1; Ka = K1; Vat = V1t; Kb2 = nullptr; Vbt2 = nullptr; Op = O1;
        nq = 2048; nk1 = 2048; nk2 = 0;
    }
    const int h = bh & 15, b = bh >> 4;
    const int T1 = nk1 >> 5, T = T1 + (cross ? (nk2 >> 5) : 0);

    // Q frags straight from global: B-operand, n=l15 (q), k=ks*32+g*8+j
    bf16x8 qf[2][2];
#pragma unroll
    for (int qb = 0; qb < 2; qb++) {
        const bf16* qrow = Qp + ((size_t)bh * nq + q0 + (wave << 5) + (qb << 4) + l15) * 64;
        qf[qb][0] = *(const bf16x8*)(qrow + (g << 3));
        qf[qb][1] = *(const bf16x8*)(qrow + 32 + (g << 3));
    }

    // all-ones A-fragment for the rowsum MFMA
    bf16x8 ones;
#pragma unroll
    for (int z = 0; z < 8; z++) ones[z] = (bf16)1.0f;

    f32x4 Oacc[4][2] = {}, Ofin[4][2] = {};
    f32x4 Lones[2] = {};            // rowsum accumulators (all lanes replicated)
    const float gmul = cross ? tanhf(gate[h]) : 1.0f;

    // per-thread incremental staging pointers
    const int kr = tid >> 3, kc = (tid & 7) ^ (kr & 7);
    const int vr = tid >> 2, vc = (tid & 3) ^ (vr & 3);
    const bf16* kaddr = Ka + ((size_t)bh * nk1) * 64 + (kr << 6) + (kc << 3);
    const bf16* vaddr = Vat + ((size_t)bh << 6) * nk1 + (size_t)vr * nk1 + (vc << 3);
    int staged = 0;

    auto stage = [&](int bsel) {
        if (cross && staged == T1) {   // switch to q-KV segment
            kaddr = Kb2 + ((size_t)bh * nk2) * 64 + (kr << 6) + (kc << 3);
            vaddr = Vbt2 + ((size_t)bh << 6) * nk2 + (size_t)vr * nk2 + (vc << 3);
        }
        char* Kd = (char*)fsm + (bsel << 12);
        char* Vd = (char*)fsm + 8192 + (bsel << 12);
        const int wb = (tid & 192) << 4;
        gl16(kaddr, Kd + wb);
        gl16(vaddr, Vd + wb);
        kaddr += 2048;    // 32 rows x 64
        vaddr += 32;      // 32 tokens
        staged++;
    };

    auto compute = [&](int t, int bsel) {
        const char* Kb = (const char*)fsm + (bsel << 12);
        const char* Vb = (const char*)fsm + 8192 + (bsel << 12);
        // S^T = K Q^T : 8 MFMAs. Lane (l15,g) gets tokens 4g+r (nb=0),
        // 16+4g+r (nb=1) for q=l15.
        f32x4 S[2][2];
#pragma unroll
        for (int nb = 0; nb < 2; nb++) {
            int row = (nb << 4) + l15;
            bf16x8 kf0 = *(const bf16x8*)(Kb + (row << 7) + ((g ^ (row & 7)) << 4));
            bf16x8 kf1 = *(const bf16x8*)(Kb + (row << 7) + (((4 + g) ^ (row & 7)) << 4));
#pragma unroll
            for (int qb = 0; qb < 2; qb++) {
                f32x4 s = {};
                s = __builtin_amdgcn_mfma_f32_16x16x32_bf16(kf0, qf[qb][0], s, 0, 0, 0);
                s = __builtin_amdgcn_mfma_f32_16x16x32_bf16(kf1, qf[qb][1], s, 0, 0, 0);
                S[nb][qb] = s;
            }
        }
        // exp2 -> P straight into B-frag registers (pi-matched V layout)
        bf16x8 pf[2];
#pragma unroll
        for (int qb = 0; qb < 2; qb++)
#pragma unroll
            for (int r = 0; r < 4; r++) {
                pf[qb][r]     = (bf16)__builtin_amdgcn_exp2f(S[0][qb][r]);
                pf[qb][4 + r] = (bf16)__builtin_amdgcn_exp2f(S[1][qb][r]);
            }
        // rowsums via ones-MFMA (accumulates across steps; every lane holds
        // sum_k P[k][q=l15] in all 4 accumulator slots)
#pragma unroll
        for (int qb = 0; qb < 2; qb++)
            Lones[qb] = __builtin_amdgcn_mfma_f32_16x16x32_bf16(
                ones, pf[qb], Lones[qb], 0, 0, 0);
        // O^T += Vt' @ P^T : 8 MFMAs
#pragma unroll
        for (int hb = 0; hb < 4; hb++) {
            int row = (hb << 4) + l15;
            bf16x8 vf = *(const bf16x8*)(Vb + (row << 6) + ((g ^ (row & 3)) << 4));
#pragma unroll
            for (int qb = 0; qb < 2; qb++)
                Oacc[hb][qb] = __builtin_amdgcn_mfma_f32_16x16x32_bf16(
                    vf, pf[qb], Oacc[hb][qb], 0, 0, 0);
        }
        if (cross && t == T1 - 1) {   // gated-segment flush
#pragma unroll
            for (int qb = 0; qb < 2; qb++) {
                float w = gmul / Lones[qb][0];
#pragma unroll
                for (int hb = 0; hb < 4; hb++)
#pragma unroll
                    for (int r = 0; r < 4; r++) {
                        Ofin[hb][qb][r] += Oacc[hb][qb][r] * w;
                        Oacc[hb][qb][r] = 0.0f;
                    }
                Lones[qb] = f32x4{};
            }
        }
    };

    stage(0);
    for (int t = 0; t < T; t++) {
        int bsel = t & 1;
        if (t + 1 < T) { stage(bsel ^ 1); BAR_VM2(); }
        else           { BAR_VM0(); }
        compute(t, bsel);
        BAR();
    }

    // final weights (rowsums already reduced by the ones-MFMA)
    float wfin[2];
#pragma unroll
    for (int qb = 0; qb < 2; qb++)
        wfin[qb] = (cross ? 1.0f : gmul) / Lones[qb][0];

    // epilogue: O^T regs -> LDS [hd=64][q=128] stride 136 -> coalesced stores
    bf16* OB = fsm;
#pragma unroll
    for (int hb = 0; hb < 4; hb++)
#pragma unroll
        for (int qb = 0; qb < 2; qb++)
#pragma unroll
            for (int r = 0; r < 4; r++) {
                float v = Oacc[hb][qb][r] * wfin[qb];
                if (cross) v += Ofin[hb][qb][r];
                OB[((hb << 4) + (g << 2) + r) * 136 + (wave << 5) + (qb << 4) + l15] = (bf16)v;
            }
    __syncthreads();
    {
        int q = tid >> 1, half = (tid & 1) << 5;
        bf16x8 o[4];
#pragma unroll
        for (int j2 = 0; j2 < 4; j2++)
#pragma unroll
            for (int jj = 0; jj < 8; jj++)
                o[j2][jj] = OB[(half + (j2 << 3) + jj) * 136 + q];
        bf16* op = Op + (((size_t)b * nq + q0 + q) << 10) + (h << 6) + half;
#pragma unroll
        for (int j2 = 0; j2 < 4; j2++)
            *(bf16x8*)(op + (j2 << 3)) = o[j2];
    }
}

// ---------------------------------------------------------------------------
extern "C" void kernel_launch(void* const* d_in, const int* in_sizes, int n_in,
                              void* d_out, int out_size, void* d_ws, size_t ws_size,
                              hipStream_t stream)
{
    const float* x       = (const float*)d_in[0];
    const float* query   = (const float*)d_in[1];
    const float* lowres  = (const float*)d_in[2];
    const float* W_qkv   = (const float*)d_in[3];
    const float* W_xkv   = (const float*)d_in[4];
    const float* W_qlin  = (const float*)d_in[5];
    const float* gate    = (const float*)d_in[6];
    const float* W_proj  = (const float*)d_in[7];
    const float* b_proj  = (const float*)d_in[8];
    const float* W_qproj = (const float*)d_in[9];
    const float* b_qproj = (const float*)d_in[10];
    const float* W_lr    = (const float*)d_in[11];
    const float* b_lr    = (const float*)d_in[12];
    float* out = (float*)d_out;

    const float sc2 = 0.125f * 1.44269504088896f;   // scale*log2e, folded into Q

    char* ws = (char*)d_ws;
    bf16* WtX     = (bf16*)ws; ws += 10485760;  // [5120][1024] = qkv|xkv transposed
    bf16* Wtqlin  = (bf16*)ws; ws += 6291456;
    bf16* Wtproj  = (bf16*)ws; ws += 2097152;
    bf16* Wtqproj = (bf16*)ws; ws += 2097152;
    bf16* xb      = (bf16*)ws; ws += 8388608;   // ax aliases (xb dead by then)
    bf16* qryb    = (bf16*)ws; ws += 2097152;   // aq aliases
    bf16* qb      = (bf16*)ws; ws += 8388608;
    bf16* kb      = (bf16*)ws; ws += 8388608;
    bf16* vbt     = (bf16*)ws; ws += 8388608;   // [bh][64][2048] pi-permuted
    bf16* k2      = (bf16*)ws; ws += 8388608;
    bf16* v2t     = (bf16*)ws; ws += 8388608;   // [bh][64][2048] pi-permuted
    bf16* qq      = (bf16*)ws; ws += 2097152;
    bf16* qk      = (bf16*)ws; ws += 2097152;
    bf16* qvt     = (bf16*)ws; ws += 2097152;   // [bh][64][512] pi-permuted
    bf16* ax = xb;
    bf16* aq = qryb;

    // 1: casts + weight transposes + lr_out (all input-only)
    prep<<<5248, 256, 0, stream>>>(
        x, xb, query, qryb, W_qkv, W_xkv, W_qlin, W_proj, W_qproj,
        WtX, Wtqlin, Wtproj, Wtqproj, lowres, W_lr, b_lr, out + 5242880);

    // 2: x @ [W_qkv|W_xkv] -> q,k,v,k2,v2  +  query @ W_qlin -> qq,qk,qv
    gemm_qkv<<<1472, 256, 0, stream>>>(
        xb, WtX, qb, kb, vbt, k2, v2t, qryb, Wtqlin, qq, qk, qvt, sc2);

    // 3: merged attention: 512 self-attn + 128 cross-attn blocks, XCD-balanced
    flash3m<<<640, 256, 0, stream>>>(
        qb, kb, vbt, ax, qq, k2, v2t, qk, qvt, aq, gate);

    // 4: output projections
    gemm_proj<<<320, 256, 0, stream>>>(
        ax, Wtproj, out, b_proj, aq, Wtqproj, out + 4194304, b_qproj);

    (void)in_sizes; (void)n_in; (void)out_size; (void)ws_size;
}

// Round 12
// 277.171 us; speedup vs baseline: 1.0609x; 1.0277x over previous
//
#include <hip/hip_runtime.h>

typedef __bf16 bf16;
typedef __bf16 bf16x4 __attribute__((ext_vector_type(4)));
typedef __bf16 bf16x8 __attribute__((ext_vector_type(8)));
typedef float  f32x4  __attribute__((ext_vector_type(4)));

// B=2, N=2048, QN=512, D=QD=1024, H=QH=16, HD=64. fp32 in/out, bf16 MFMA.

#define AS1(p) ((const __attribute__((address_space(1))) void*)(p))
#define AS3(p) ((__attribute__((address_space(3))) void*)(p))
__device__ __forceinline__ void gl16(const void* g, void* l) {
    __builtin_amdgcn_global_load_lds(AS1(g), AS3(l), 16, 0, 0);
}
// soft barriers: per-wave bounded vmcnt wait; prefetch loads stay in flight.
#define BAR_VM4() asm volatile("s_waitcnt vmcnt(4)\n\ts_barrier" ::: "memory")
#define BAR_VM2() asm volatile("s_waitcnt vmcnt(2)\n\ts_barrier" ::: "memory")
#define BAR_VM0() asm volatile("s_waitcnt vmcnt(0)\n\ts_barrier" ::: "memory")
#define BAR()     asm volatile("s_barrier" ::: "memory")

// ---------------------------------------------------------------------------
// prep: fused cast (blocks 0..2559) + weight-transpose (2560..5119) + lr_out
// (5120..5247). All independent input-only work -> one launch.
// ---------------------------------------------------------------------------
__global__ __launch_bounds__(256) void prep(
    const float* __restrict__ x, bf16* __restrict__ xb,
    const float* __restrict__ query, bf16* __restrict__ qryb,
    const float* __restrict__ W_qkv, const float* __restrict__ W_xkv,
    const float* __restrict__ W_qlin, const float* __restrict__ W_proj,
    const float* __restrict__ W_qproj,
    bf16* __restrict__ WtX, bf16* __restrict__ Wtqlin,
    bf16* __restrict__ Wtproj, bf16* __restrict__ Wtqproj,
    const float* __restrict__ lowres, const float* __restrict__ W_lr,
    const float* __restrict__ b_lr, float* __restrict__ lrout)
{
    __shared__ float T[64][65];
    const int bid = blockIdx.x, tid = threadIdx.x;

    if (bid < 2560) {
        // ---- fp32 -> bf16 cast for x and query ----
        int idx = (bid * 256 + tid) << 3;
        const float* s; bf16* d;
        if (idx < 4194304) { s = x + idx; d = xb + idx; }
        else { int k = idx - 4194304; s = query + k; d = qryb + k; }
        f32x4 a = *(const f32x4*)s, c = *(const f32x4*)(s + 4);
        bf16x8 v;
#pragma unroll
        for (int j = 0; j < 4; j++) { v[j] = (bf16)a[j]; v[4 + j] = (bf16)c[j]; }
        *(bf16x8*)d = v;
    } else if (bid < 5120) {
        // ---- weights [1024][N] fp32 -> bf16 transposed [N][1024] ----
        int w = bid - 2560;
        int gx = w % 160, k0 = (w / 160) << 6;
        const float* S; bf16* D; int N;
        if (gx < 48)       { S = W_qkv;   D = WtX;     N = 3072; }
        else if (gx < 80)  { S = W_xkv;   D = WtX + (size_t)3072 * 1024; N = 2048; gx -= 48; }
        else if (gx < 128) { S = W_qlin;  D = Wtqlin;  N = 3072; gx -= 80; }
        else if (gx < 144) { S = W_proj;  D = Wtproj;  N = 1024; gx -= 128; }
        else               { S = W_qproj; D = Wtqproj; N = 1024; gx -= 144; }
        int n0 = gx << 6;
#pragma unroll
        for (int rr = 0; rr < 4; rr++) {
            int row = (rr << 4) + (tid >> 4), col = (tid & 15) << 2;
            f32x4 v = *(const f32x4*)(S + (size_t)(k0 + row) * N + n0 + col);
#pragma unroll
            for (int j = 0; j < 4; j++) T[col + j][row] = v[j];
        }
        __syncthreads();
        {
            int n = tid >> 2, kc = (tid & 3) << 4;
            bf16x8 v0, v1;
#pragma unroll
            for (int j = 0; j < 8; j++) {
                v0[j] = (bf16)T[n][kc + j];
                v1[j] = (bf16)T[n][kc + 8 + j];
            }
            bf16* dp = D + (size_t)(n0 + n) * 1024 + k0 + kc;
            *(bf16x8*)dp = v0; *(bf16x8*)(dp + 8) = v1;
        }
    } else {
        // ---- lr_out[b,i,j] ----
        int idx = (bid - 5120) * 256 + tid;
        int j = idx & 63, i = (idx >> 6) & 255, b = idx >> 14;
        float acc = b_lr[j];
        const float* lr = lowres + ((size_t)b << 14);
        for (int k = 0; k < 64; k++) {
            int f = i * 64 + k;
            acc += lr[((f & 255) << 6) + (f >> 8)] * W_lr[(k << 6) + j];
        }
        lrout[idx] = acc;
    }
}

// ---------------------------------------------------------------------------
// GEMM core: C[M,N] = A[M,K] @ Bt[N,K]^T, 128x128 tile, BK=32, LDS
// double-buffered global_load_lds staging, soft barriers (vmcnt(4)).
// LDS swizzle: slot s of row r holds chunk s ^ ((r^(r>>2))&3)  (2-way, free).
// Epilogue staging uses stride-72 pad (36KB total). NOTE (round-9 lesson):
// occupancy here is VGPR-capped (88 -> 128-granule -> 4 blocks/CU), so
// shrinking LDS to 32KB buys nothing, while the stride-64 epilogue costs
// +2M bank-conflict cycles (+7us). Stride-72 is load-bearing.
// NSPLIT>0: epilogue scatters 64-col head-blocks into per-head buffers via
// LDS round-trip; vmask bit per split = write transposed [bh][hd][ntok].
// V outputs are written with per-32-token-tile group permutation pi^-1 so the
// flash kernel consumes P straight from the S-output register layout:
//   pi(8g+j) = 4g + (j&3) + 16*(j>>2).
// s0scale multiplies split 0 (pre-scales Q for attention).
// ---------------------------------------------------------------------------
template <int NSPLIT, typename OT>
__device__ __forceinline__ void gemm_core(
    bf16* gsm,
    const bf16* __restrict__ A, const bf16* __restrict__ Bt,
    OT* __restrict__ C0, OT* __restrict__ C1, OT* __restrict__ C2,
    OT* __restrict__ C3, OT* __restrict__ C4,
    const float* __restrict__ bias, int N, int K, int tshift,
    float s0scale, unsigned vmask, int bx, int by)
{
    const int tid  = threadIdx.x;
    const int wave = tid >> 6, lane = tid & 63;
    const int l15  = lane & 15, g = lane >> 4;
    const int wr   = wave & 1, wc = wave >> 1;
    const int m0   = by << 7, n0 = bx << 7;

    f32x4 acc[4][4] = {};

    auto stage = [&](int t, int bsel) {
        const bf16* Ab = A  + (size_t)m0 * K + (t << 5);
        const bf16* Bb = Bt + (size_t)n0 * K + (t << 5);
        char* Ad = (char*)gsm + (bsel << 14);
        char* Bd = Ad + 8192;
        const int wb = (tid & 192) << 4;
#pragma unroll
        for (int i = 0; i < 2; i++) {
            int L = (i << 8) + tid;
            int r = L >> 2, c = (L & 3) ^ ((r ^ (r >> 2)) & 3);
            gl16(Ab + (size_t)r * K + (c << 3), Ad + (i << 12) + wb);
            gl16(Bb + (size_t)r * K + (c << 3), Bd + (i << 12) + wb);
        }
    };
    auto compute = [&](int bsel) {
        const char* Ad = (const char*)gsm + (bsel << 14);
        const char* Bd = Ad + 8192;
        bf16x8 af[4], bq[4];
#pragma unroll
        for (int mb = 0; mb < 4; mb++) {
            int row = (wr << 6) + (mb << 4) + l15;
            af[mb] = *(const bf16x8*)(Ad + (row << 6)
                      + ((g ^ ((row ^ (row >> 2)) & 3)) << 4));
        }
#pragma unroll
        for (int nb = 0; nb < 4; nb++) {
            int row = (wc << 6) + (nb << 4) + l15;
            bq[nb] = *(const bf16x8*)(Bd + (row << 6)
                      + ((g ^ ((row ^ (row >> 2)) & 3)) << 4));
        }
#pragma unroll
        for (int mb = 0; mb < 4; mb++)
#pragma unroll
            for (int nb = 0; nb < 4; nb++)
                acc[mb][nb] = __builtin_amdgcn_mfma_f32_16x16x32_bf16(
                    af[mb], bq[nb], acc[mb][nb], 0, 0, 0);
    };

    const int T = K >> 5;
    stage(0, 0);
    for (int t = 0; t < T; t++) {
        int bsel = t & 1;
        if (t + 1 < T) { stage(t + 1, bsel ^ 1); BAR_VM4(); }
        else           { BAR_VM0(); }
        compute(bsel);
        BAR();
    }

    if constexpr (NSPLIT == 0) {
#pragma unroll
        for (int mb = 0; mb < 4; mb++)
#pragma unroll
            for (int nb = 0; nb < 4; nb++) {
                int n = n0 + (wc << 6) + (nb << 4) + l15;
                int mbase = m0 + (wr << 6) + (mb << 4) + (g << 2);
                float bi = bias[n];
#pragma unroll
                for (int r = 0; r < 4; r++)
                    C0[(size_t)(mbase + r) * N + n] = (OT)(acc[mb][nb][r] + bi);
            }
    } else {
        BAR();
        bf16* stg = gsm + wave * 4608;
        const int nh = (n0 >> 6) + wc;
        const int sl = nh >> 4, hq = nh & 15;
        const float scl = (sl == 0) ? s0scale : 1.0f;
        const bool isv = (vmask >> sl) & 1;
        if (isv) {   // stage transposed [hd][t], stride 72
#pragma unroll
            for (int mb = 0; mb < 4; mb++)
#pragma unroll
                for (int nb = 0; nb < 4; nb++)
#pragma unroll
                    for (int r = 0; r < 4; r++)
                        stg[((nb << 4) + l15) * 72 + (mb << 4) + (g << 2) + r]
                            = (bf16)(acc[mb][nb][r] * scl);
        } else {     // stage [t][hd], stride 64
#pragma unroll
            for (int mb = 0; mb < 4; mb++)
#pragma unroll
                for (int nb = 0; nb < 4; nb++)
#pragma unroll
                    for (int r = 0; r < 4; r++)
                        stg[((mb << 4) + (g << 2) + r) << 6 | ((nb << 4) + l15)]
                            = (bf16)(acc[mb][nb][r] * scl);
        }
        __syncthreads();
        const int ntok = 1 << tshift;
        const int tok0 = m0 + (wr << 6);
        const int b = tok0 >> tshift, t0 = tok0 & (ntok - 1);
        const int bh_ = (b << 4) + hq;
        OT* dst = (sl == 0) ? C0 : (sl == 1) ? C1 : (sl == 2) ? C2
                : (sl == 3) ? C3 : C4;
#pragma unroll
        for (int rr = 0; rr < 8; rr++) {
            int idx = (rr << 6) + lane;
            int rowi = idx >> 3, c = idx & 7;
            if (isv) {
                // pi-permuted store: tokens in 4-groups; group gamma goes to
                // position group piinv(gamma) = 2*(gamma&3) + (gamma>>2).
                bf16x8 vv = *(const bf16x8*)&stg[rowi * 72 + (c << 3)];
                bf16x4 lo, hi;
#pragma unroll
                for (int jj = 0; jj < 4; jj++) { lo[jj] = vv[jj]; hi[jj] = vv[4 + jj]; }
                int tb = t0 + ((c >> 2) << 5);          // 32-token tile base
                int gamma0 = (c << 1) & 7;              // even token-group
                int p_lo = (((gamma0 & 3) << 1) + (gamma0 >> 2)) << 2;
                size_t base = ((size_t)((bh_ << 6) + rowi)) * ntok + tb;
                *(bf16x4*)&dst[base + p_lo] = lo;
                *(bf16x4*)&dst[base + p_lo + 8] = hi;
            } else {
                bf16x8 vv = *(const bf16x8*)&stg[(rowi << 6) + (c << 3)];
                *(bf16x8*)&dst[(((size_t)bh_ * ntok + t0 + rowi) << 6) + (c << 3)] = vv;
            }
        }
    }
}

// ---------------------------------------------------------------------------
// 64x64-tile GEMM core for the output projections (direct crop of gemm_core:
// identical stage/swizzle/read algebra, acc[2][2], 2 gl16/thread, vmcnt(2),
// 16KB LDS). Purpose: 4x the block count of the 128^2 core -> 5 blocks/CU
// (20 waves/CU) instead of 1.25 -> latency hiding for the K-loop chain.
// ---------------------------------------------------------------------------
__device__ __forceinline__ void gemm_core64(
    bf16* gsm,
    const bf16* __restrict__ A, const bf16* __restrict__ Bt,
    float* __restrict__ C, const float* __restrict__ bias,
    int N, int K, int bx, int by)
{
    const int tid  = threadIdx.x;
    const int wave = tid >> 6, lane = tid & 63;
    const int l15  = lane & 15, g = lane >> 4;
    const int wr   = wave & 1, wc = wave >> 1;
    const int m0   = by << 6, n0 = bx << 6;

    f32x4 acc[2][2] = {};

    const int sr = tid >> 2, sc = (tid & 3) ^ ((sr ^ (sr >> 2)) & 3);

    auto stage = [&](int t, int bsel) {
        const bf16* Ab = A  + (size_t)(m0 + sr) * K + (t << 5) + (sc << 3);
        const bf16* Bb = Bt + (size_t)(n0 + sr) * K + (t << 5) + (sc << 3);
        char* Ad = (char*)gsm + (bsel << 13);
        const int wb = (tid & 192) << 4;
        gl16(Ab, Ad + wb);
        gl16(Bb, Ad + 4096 + wb);
    };
    auto compute = [&](int bsel) {
        const char* Ad = (const char*)gsm + (bsel << 13);
        const char* Bd = Ad + 4096;
        bf16x8 af[2], bq[2];
#pragma unroll
        for (int mb = 0; mb < 2; mb++) {
            int row = (wr << 5) + (mb << 4) + l15;
            af[mb] = *(const bf16x8*)(Ad + (row << 6)
                      + ((g ^ ((row ^ (row >> 2)) & 3)) << 4));
        }
#pragma unroll
        for (int nb = 0; nb < 2; nb++) {
            int row = (wc << 5) + (nb << 4) + l15;
            bq[nb] = *(const bf16x8*)(Bd + (row << 6)
                      + ((g ^ ((row ^ (row >> 2)) & 3)) << 4));
        }
#pragma unroll
        for (int mb = 0; mb < 2; mb++)
#pragma unroll
            for (int nb = 0; nb < 2; nb++)
                acc[mb][nb] = __builtin_amdgcn_mfma_f32_16x16x32_bf16(
                    af[mb], bq[nb], acc[mb][nb], 0, 0, 0);
    };

    const int T = K >> 5;
    stage(0, 0);
    for (int t = 0; t < T; t++) {
        int bsel = t & 1;
        if (t + 1 < T) { stage(t + 1, bsel ^ 1); BAR_VM2(); }
        else           { BAR_VM0(); }
        compute(bsel);
        BAR();
    }

#pragma unroll
    for (int mb = 0; mb < 2; mb++)
#pragma unroll
        for (int nb = 0; nb < 2; nb++) {
            int n = n0 + (wc << 5) + (nb << 4) + l15;
            int mbase = m0 + (wr << 5) + (mb << 4) + (g << 2);
            float bi = bias[n];
#pragma unroll
            for (int r = 0; r < 4; r++)
                C[(size_t)(mbase + r) * N + n] = acc[mb][nb][r] + bi;
        }
}

// ---------------------------------------------------------------------------
// Fused front GEMMs, 2D-supertile XCD swizzle. 1472 = 8 XCDs x 184 slots.
// GEMM1 (x @ [W_qkv|W_xkv], 40x32 tiles): slot s<160 -> XCD owns a 5-wide
// bx column band (B working set 1.3MB stays L2-resident); within it, 4x5
// supertiles sweep by. bx = 5*xcd + s%5, by = 4*(s/20) + (s%20)/5.
// GEMM2 (query @ W_qlin, 24x8 tiles): s>=160 -> by = xcd, bx = s-160.
// ---------------------------------------------------------------------------
__global__ __launch_bounds__(256) void gemm_qkv(
    const bf16* __restrict__ A0, const bf16* __restrict__ Bt0,
    bf16* __restrict__ qb, bf16* __restrict__ kb, bf16* __restrict__ vbt,
    bf16* __restrict__ k2, bf16* __restrict__ v2t,
    const bf16* __restrict__ A1, const bf16* __restrict__ Bt1,
    bf16* __restrict__ qq, bf16* __restrict__ qk, bf16* __restrict__ qvt,
    float sc2)
{
    __shared__ __align__(16) bf16 gsm[18432];
    const int xcd = blockIdx.x & 7, s = blockIdx.x >> 3;
    const bf16 *A, *Bt; bf16 *C0, *C1, *C2, *C3, *C4;
    int N, tshift, bx, by; unsigned vmask;
    if (s < 160) {
        int k = s / 20, w = s % 20;
        by = (k << 2) + w / 5; bx = xcd * 5 + w % 5;
        A = A0; Bt = Bt0; C0 = qb; C1 = kb; C2 = vbt; C3 = k2; C4 = v2t;
        N = 5120; tshift = 11; vmask = 0b10100u;
    } else {
        by = xcd; bx = s - 160;
        A = A1; Bt = Bt1; C0 = qq; C1 = qk; C2 = qvt; C3 = nullptr; C4 = nullptr;
        N = 3072; tshift = 9; vmask = 0b100u;
    }
    gemm_core<1, bf16>(gsm, A, Bt, C0, C1, C2, C3, C4, nullptr,
                       N, 1024, tshift, sc2, vmask, bx, by);
}

// ---------------------------------------------------------------------------
// Fused output projections on the 64x64 core: ax @ W_proj (1024 blocks,
// 16x64 tiles) and aq @ W_qproj (256 blocks, 16x16 tiles), one launch.
// Grid 1280 = 8 XCDs x 160, chunked bijective: contiguous slots per XCD
// share A row-bands; B (2MB bf16) L2-resident per XCD.
// ---------------------------------------------------------------------------
__global__ __launch_bounds__(256) void gemm_proj(
    const bf16* __restrict__ ax, const bf16* __restrict__ Wtp,
    float* __restrict__ o0, const float* __restrict__ bp,
    const bf16* __restrict__ aq, const bf16* __restrict__ Wtq,
    float* __restrict__ o1, const float* __restrict__ bq)
{
    __shared__ __align__(16) bf16 gsm[8192];   // 16KB: 2 bufs x (A 4KB | B 4KB)
    int idx = (blockIdx.x & 7) * 160 + (blockIdx.x >> 3);
    const bf16 *A, *Bt; float* C; const float* bias; int bx, by;
    if (idx < 1024) { A = ax; Bt = Wtp; C = o0; bias = bp; bx = idx & 15; by = idx >> 4; }
    else { idx -= 1024; A = aq; Bt = Wtq; C = o1; bias = bq; bx = idx & 15; by = idx >> 4; }
    gemm_core64(gsm, A, Bt, C, bias, 1024, 1024, bx, by);
}

// ---------------------------------------------------------------------------
// Merged flash attention, S^T form, q-tile 128 over 4 waves (32 q/wave),
// k-tile 32, fixed-max softmax (Q pre-scaled to log2 domain), double-buffered
// global_load_lds K/V staging, soft barriers (vmcnt(2), never drained).
// P stays fully in registers: Vt is stored pi-permuted (see gemm_core), so the
// S-output register layout IS the PV B-operand layout (zero P data movement).
// Rowsums via ones-MFMA: Lones[qb] = mfma(ones, pf[qb], Lones[qb]) makes every
// lane's accumulator hold sum_k P[k][q=l15] (accumulated across steps, no VALU
// adds, no shuffles).  Staging uses per-thread incremental global pointers.
// NOTE (round-10 lesson): s_setprio around the MFMA clusters REGRESSED this
// kernel (80 -> 87.7us): the 4 waves are barrier-locked (no role diversity,
// T5 null regime) and the insertion perturbed regalloc (VGPR 80 -> 88,
// occupancy 19.4 -> 14.4). Do not re-add.
// Grid 640 = 8 XCDs x 80. Decode: xcd j = blockIdx&7, slot i = blockIdx>>3.
//   i < 16 : cross-attn (longest first), bh = 4j + (i>>2), qtile = i&3;
//            seg0 = x-KV nk=2048 * tanh(gate), seg1 = q-KV nk=512 weight 1.
//   i >= 16: self-attn, bh = 4j + ((i-16)>>4), qtile = (i-16)&15, nk=2048.
// Q [bh][nq][64], K [bh][nk][64], Vt' [bh][64][nk] (pi-permuted),
// O [b][nq][16*64].  LDS 17.4KB: K 2x4KB | V 2x4KB (epilogue reuses as OB).
// ---------------------------------------------------------------------------
__global__ __launch_bounds__(256) void flash3m(
    const bf16* __restrict__ Q1, const bf16* __restrict__ K1,
    const bf16* __restrict__ V1t, bf16* __restrict__ O1,
    const bf16* __restrict__ Q2, const bf16* __restrict__ K2a,
    const bf16* __restrict__ V2at, const bf16* __restrict__ K2b,
    const bf16* __restrict__ V2bt, bf16* __restrict__ O2,
    const float* __restrict__ gate)
{
    // bytes: K bufs [0,8192), V bufs [8192,16384); epilogue OB [0,17408)
    __shared__ __align__(16) bf16 fsm[8704];

    const int tid = threadIdx.x;
    const int wave = tid >> 6, lane = tid & 63;
    const int l15 = lane & 15, g = lane >> 4;

    const int j = blockIdx.x & 7, i = blockIdx.x >> 3;
    const bf16 *Qp, *Ka, *Vat, *Kb2, *Vbt2; bf16* Op;
    int nq, nk1, nk2, q0, bh;
    bool cross;
    if (i < 16) {
        cross = true;
        bh = (j << 2) + (i >> 2); q0 = (i & 3) << 7;
        Qp = Q2; Ka = K2a; Vat = V2at; Kb2 = K2b; Vbt2 = V2bt; Op = O2;
        nq = 512; nk1 = 2048; nk2 = 512;
    } else {
        cross = false;
        int is = i - 16;
        bh = (j << 2) + (is >> 4); q0 = (is & 15) << 7;
        Qp = Q1; Ka = K1; Vat = V1t; Kb2 = nullptr; Vbt2 = nullptr; Op = O1;
        nq = 2048; nk1 = 2048; nk2 = 0;
    }
    const int h = bh & 15, b = bh >> 4;
    const int T1 = nk1 >> 5, T = T1 + (cross ? (nk2 >> 5) : 0);

    // Q frags straight from global: B-operand, n=l15 (q), k=ks*32+g*8+j
    bf16x8 qf[2][2];
#pragma unroll
    for (int qb = 0; qb < 2; qb++) {
        const bf16* qrow = Qp + ((size_t)bh * nq + q0 + (wave << 5) + (qb << 4) + l15) * 64;
        qf[qb][0] = *(const bf16x8*)(qrow + (g << 3));
        qf[qb][1] = *(const bf16x8*)(qrow + 32 + (g << 3));
    }

    // all-ones A-fragment for the rowsum MFMA
    bf16x8 ones;
#pragma unroll
    for (int z = 0; z < 8; z++) ones[z] = (bf16)1.0f;

    f32x4 Oacc[4][2] = {}, Ofin[4][2] = {};
    f32x4 Lones[2] = {};            // rowsum accumulators (all lanes replicated)
    const float gmul = cross ? tanhf(gate[h]) : 1.0f;

    // per-thread incremental staging pointers
    const int kr = tid >> 3, kc = (tid & 7) ^ (kr & 7);
    const int vr = tid >> 2, vc = (tid & 3) ^ (vr & 3);
    const bf16* kaddr = Ka + ((size_t)bh * nk1) * 64 + (kr << 6) + (kc << 3);
    const bf16* vaddr = Vat + ((size_t)bh << 6) * nk1 + (size_t)vr * nk1 + (vc << 3);
    int staged = 0;

    auto stage = [&](int bsel) {
        if (cross && staged == T1) {   // switch to q-KV segment
            kaddr = Kb2 + ((size_t)bh * nk2) * 64 + (kr << 6) + (kc << 3);
            vaddr = Vbt2 + ((size_t)bh << 6) * nk2 + (size_t)vr * nk2 + (vc << 3);
        }
        char* Kd = (char*)fsm + (bsel << 12);
        char* Vd = (char*)fsm + 8192 + (bsel << 12);
        const int wb = (tid & 192) << 4;
        gl16(kaddr, Kd + wb);
        gl16(vaddr, Vd + wb);
        kaddr += 2048;    // 32 rows x 64
        vaddr += 32;      // 32 tokens
        staged++;
    };

    auto compute = [&](int t, int bsel) {
        const char* Kb = (const char*)fsm + (bsel << 12);
        const char* Vb = (const char*)fsm + 8192 + (bsel << 12);
        // S^T = K Q^T : 8 MFMAs. Lane (l15,g) gets tokens 4g+r (nb=0),
        // 16+4g+r (nb=1) for q=l15.
        f32x4 S[2][2];
#pragma unroll
        for (int nb = 0; nb < 2; nb++) {
            int row = (nb << 4) + l15;
            bf16x8 kf0 = *(const bf16x8*)(Kb + (row << 7) + ((g ^ (row & 7)) << 4));
            bf16x8 kf1 = *(const bf16x8*)(Kb + (row << 7) + (((4 + g) ^ (row & 7)) << 4));
#pragma unroll
            for (int qb = 0; qb < 2; qb++) {
                f32x4 s = {};
                s = __builtin_amdgcn_mfma_f32_16x16x32_bf16(kf0, qf[qb][0], s, 0, 0, 0);
                s = __builtin_amdgcn_mfma_f32_16x16x32_bf16(kf1, qf[qb][1], s, 0, 0, 0);
                S[nb][qb] = s;
            }
        }
        // exp2 -> P straight into B-frag registers (pi-matched V layout)
        bf16x8 pf[2];
#pragma unroll
        for (int qb = 0; qb < 2; qb++)
#pragma unroll
            for (int r = 0; r < 4; r++) {
                pf[qb][r]     = (bf16)__builtin_amdgcn_exp2f(S[0][qb][r]);
                pf[qb][4 + r] = (bf16)__builtin_amdgcn_exp2f(S[1][qb][r]);
            }
        // rowsums via ones-MFMA (accumulates across steps; every lane holds
        // sum_k P[k][q=l15] in all 4 accumulator slots)
#pragma unroll
        for (int qb = 0; qb < 2; qb++)
            Lones[qb] = __builtin_amdgcn_mfma_f32_16x16x32_bf16(
                ones, pf[qb], Lones[qb], 0, 0, 0);
        // O^T += Vt' @ P^T : 8 MFMAs
#pragma unroll
        for (int hb = 0; hb < 4; hb++) {
            int row = (hb << 4) + l15;
            bf16x8 vf = *(const bf16x8*)(Vb + (row << 6) + ((g ^ (row & 3)) << 4));
#pragma unroll
            for (int qb = 0; qb < 2; qb++)
                Oacc[hb][qb] = __builtin_amdgcn_mfma_f32_16x16x32_bf16(
                    vf, pf[qb], Oacc[hb][qb], 0, 0, 0);
        }
        if (cross && t == T1 - 1) {   // gated-segment flush
#pragma unroll
            for (int qb = 0; qb < 2; qb++) {
                float w = gmul / Lones[qb][0];
#pragma unroll
                for (int hb = 0; hb < 4; hb++)
#pragma unroll
                    for (int r = 0; r < 4; r++) {
                        Ofin[hb][qb][r] += Oacc[hb][qb][r] * w;
                        Oacc[hb][qb][r] = 0.0f;
                    }
                Lones[qb] = f32x4{};
            }
        }
    };

    stage(0);
    for (int t = 0; t < T; t++) {
        int bsel = t & 1;
        if (t + 1 < T) { stage(bsel ^ 1); BAR_VM2(); }
        else           { BAR_VM0(); }
        compute(t, bsel);
        BAR();
    }

    // final weights (rowsums already reduced by the ones-MFMA)
    float wfin[2];
#pragma unroll
    for (int qb = 0; qb < 2; qb++)
        wfin[qb] = (cross ? 1.0f : gmul) / Lones[qb][0];

    // epilogue: O^T regs -> LDS [hd=64][q=128] stride 136 -> coalesced stores
    bf16* OB = fsm;
#pragma unroll
    for (int hb = 0; hb < 4; hb++)
#pragma unroll
        for (int qb = 0; qb < 2; qb++)
#pragma unroll
            for (int r = 0; r < 4; r++) {
                float v = Oacc[hb][qb][r] * wfin[qb];
                if (cross) v += Ofin[hb][qb][r];
                OB[((hb << 4) + (g << 2) + r) * 136 + (wave << 5) + (qb << 4) + l15] = (bf16)v;
            }
    __syncthreads();
    {
        int q = tid >> 1, half = (tid & 1) << 5;
        bf16x8 o[4];
#pragma unroll
        for (int j2 = 0; j2 < 4; j2++)
#pragma unroll
            for (int jj = 0; jj < 8; jj++)
                o[j2][jj] = OB[(half + (j2 << 3) + jj) * 136 + q];
        bf16* op = Op + (((size_t)b * nq + q0 + q) << 10) + (h << 6) + half;
#pragma unroll
        for (int j2 = 0; j2 < 4; j2++)
            *(bf16x8*)(op + (j2 << 3)) = o[j2];
    }
}

// ---------------------------------------------------------------------------
extern "C" void kernel_launch(void* const* d_in, const int* in_sizes, int n_in,
                              void* d_out, int out_size, void* d_ws, size_t ws_size,
                              hipStream_t stream)
{
    const float* x       = (const float*)d_in[0];
    const float* query   = (const float*)d_in[1];
    const float* lowres  = (const float*)d_in[2];
    const float* W_qkv   = (const float*)d_in[3];
    const float* W_xkv   = (const float*)d_in[4];
    const float* W_qlin  = (const float*)d_in[5];
    const float* gate    = (const float*)d_in[6];
    const float* W_proj  = (const float*)d_in[7];
    const float* b_proj  = (const float*)d_in[8];
    const float* W_qproj = (const float*)d_in[9];
    const float* b_qproj = (const float*)d_in[10];
    const float* W_lr    = (const float*)d_in[11];
    const float* b_lr    = (const float*)d_in[12];
    float* out = (float*)d_out;

    const float sc2 = 0.125f * 1.44269504088896f;   // scale*log2e, folded into Q

    char* ws = (char*)d_ws;
    bf16* WtX     = (bf16*)ws; ws += 10485760;  // [5120][1024] = qkv|xkv transposed
    bf16* Wtqlin  = (bf16*)ws; ws += 6291456;
    bf16* Wtproj  = (bf16*)ws; ws += 2097152;
    bf16* Wtqproj = (bf16*)ws; ws += 2097152;
    bf16* xb      = (bf16*)ws; ws += 8388608;   // ax aliases (xb dead by then)
    bf16* qryb    = (bf16*)ws; ws += 2097152;   // aq aliases
    bf16* qb      = (bf16*)ws; ws += 8388608;
    bf16* kb      = (bf16*)ws; ws += 8388608;
    bf16* vbt     = (bf16*)ws; ws += 8388608;   // [bh][64][2048] pi-permuted
    bf16* k2      = (bf16*)ws; ws += 8388608;
    bf16* v2t     = (bf16*)ws; ws += 8388608;   // [bh][64][2048] pi-permuted
    bf16* qq      = (bf16*)ws; ws += 2097152;
    bf16* qk      = (bf16*)ws; ws += 2097152;
    bf16* qvt     = (bf16*)ws; ws += 2097152;   // [bh][64][512] pi-permuted
    bf16* ax = xb;
    bf16* aq = qryb;

    // 1: casts + weight transposes + lr_out (all input-only)
    prep<<<5248, 256, 0, stream>>>(
        x, xb, query, qryb, W_qkv, W_xkv, W_qlin, W_proj, W_qproj,
        WtX, Wtqlin, Wtproj, Wtqproj, lowres, W_lr, b_lr, out + 5242880);

    // 2: x @ [W_qkv|W_xkv] -> q,k,v,k2,v2  +  query @ W_qlin -> qq,qk,qv
    gemm_qkv<<<1472, 256, 0, stream>>>(
        xb, WtX, qb, kb, vbt, k2, v2t, qryb, Wtqlin, qq, qk, qvt, sc2);

    // 3: merged attention: 512 self-attn + 128 cross-attn blocks, XCD-balanced
    flash3m<<<640, 256, 0, stream>>>(
        qb, kb, vbt, ax, qq, k2, v2t, qk, qvt, aq, gate);

    // 4: output projections (64x64 tiles, 1280 blocks = 5/CU)
    gemm_proj<<<1280, 256, 0, stream>>>(
        ax, Wtproj, out, b_proj, aq, Wtqproj, out + 4194304, b_qproj);

    (void)in_sizes; (void)n_in; (void)out_size; (void)ws_size;
}